// Round 2
// baseline (52595.020 us; speedup 1.0000x reference)
//
#include <hip/hip_runtime.h>
#include <hip/hip_bf16.h>
#include <math.h>

#define B 64
#define T 2048
#define D 128
#define H 256
#define G 1024          // 4*H gate rows
#define K0 384          // D + H   (layer-0 concat input)
#define K1 512          // H + H   (layer-1 concat input)

__device__ __forceinline__ float sigm(float x) {
    return 1.0f / (1.0f + __expf(-x));
}
__device__ __forceinline__ float ftanh(float x) {
    x = fminf(fmaxf(x, -15.0f), 15.0f);   // avoid inf/inf -> NaN
    float e = __expf(2.0f * x);
    return (e - 1.0f) / (e + 1.0f);
}
__device__ __forceinline__ float bf2f(unsigned short u) {
    unsigned int v = ((unsigned int)u) << 16;
    return __uint_as_float(v);
}

// ---------------- prep ----------------
// out[k*G + j] = in[j*K + k]   (in: G x K row-major -> out: K x G k-major)
__global__ void k_transpose(const float* __restrict__ in, float* __restrict__ out, int K) {
    int idx = blockIdx.x * blockDim.x + threadIdx.x;
    if (idx < K * G) {
        int j = idx % G;
        int k = idx / G;
        out[idx] = in[(size_t)j * K + k];
    }
}

__global__ void k_bias_sum(const float* __restrict__ a, const float* __restrict__ b,
                           float* __restrict__ out, int n) {
    int i = blockIdx.x * blockDim.x + threadIdx.x;
    if (i < n) out[i] = a[i] + b[i];
}

// ---------------- fused 2-layer LSTM: one WG per batch ----------------
// WT0: K0 x G (rows 0..D-1 = Wih0^T, rows D..K0-1 = Whh0^T)
// WT1: K1 x G (rows 0..H-1 = Wih1^T, rows H..K1-1 = Whh1^T)
__global__ __launch_bounds__(1024) void k_lstm_fused(
    const float* __restrict__ x,       // B x T x D
    const float* __restrict__ WT0,
    const float* __restrict__ WT1,
    const float* __restrict__ b0,      // G  (bih0+bhh0)
    const float* __restrict__ b1,      // G
    __hip_bfloat16* __restrict__ seq_out)  // B x T x H
{
    __shared__ float s_xh0[K0];          // [x_t (D) | h0 (H)]
    __shared__ float s_xh1[K1];          // [h0 (H)  | h1 (H)]
    __shared__ float s_gacc[4][G];       // 16 KB partial-gate accumulators

    const int b    = blockIdx.x;
    const int tid  = threadIdx.x;
    const int kb   = tid >> 8;           // k-block 0..3
    const int j4   = tid & 255;
    const int row0 = j4 << 2;            // 4 contiguous gate columns

    if (tid < H) { s_xh0[D + tid] = 0.0f; s_xh1[H + tid] = 0.0f; }
    float c0 = 0.0f, c1 = 0.0f;          // cell states for hidden unit `tid` (tid<H)

    float4 bz0 = make_float4(0.f, 0.f, 0.f, 0.f), bz1 = bz0;
    if (kb == 0) {
        bz0 = *(const float4*)(b0 + row0);
        bz1 = *(const float4*)(b1 + row0);
    }

    const int K0P = K0 / 4;              // 96 k-values per k-block
    const int K1P = K1 / 4;              // 128
    const float* W0b = WT0 + (size_t)(kb * K0P) * G + row0;
    const float* W1b = WT1 + (size_t)(kb * K1P) * G + row0;

    __syncthreads();

    for (int t = 0; t < T; ++t) {
        if (tid < D) s_xh0[tid] = x[((size_t)b * T + t) * D + tid];
        __syncthreads();                                       // B1

        // ---- layer 0 partial gates ----
        {
            float a0 = bz0.x, a1 = bz0.y, a2 = bz0.z, a3 = bz0.w;
            const float* Wp = W0b;
            const float* xp = &s_xh0[kb * K0P];
            #pragma unroll 4
            for (int k0 = 0; k0 < K0P; k0 += 4) {
                float4 xv = *(const float4*)(xp + k0);
                float4 w0 = *(const float4*)(Wp);
                float4 w1 = *(const float4*)(Wp + G);
                float4 w2 = *(const float4*)(Wp + 2 * G);
                float4 w3 = *(const float4*)(Wp + 3 * G);
                Wp += 4 * G;
                a0 = fmaf(xv.x, w0.x, a0); a1 = fmaf(xv.x, w0.y, a1); a2 = fmaf(xv.x, w0.z, a2); a3 = fmaf(xv.x, w0.w, a3);
                a0 = fmaf(xv.y, w1.x, a0); a1 = fmaf(xv.y, w1.y, a1); a2 = fmaf(xv.y, w1.z, a2); a3 = fmaf(xv.y, w1.w, a3);
                a0 = fmaf(xv.z, w2.x, a0); a1 = fmaf(xv.z, w2.y, a1); a2 = fmaf(xv.z, w2.z, a2); a3 = fmaf(xv.z, w2.w, a3);
                a0 = fmaf(xv.w, w3.x, a0); a1 = fmaf(xv.w, w3.y, a1); a2 = fmaf(xv.w, w3.z, a2); a3 = fmaf(xv.w, w3.w, a3);
            }
            *(float4*)&s_gacc[kb][row0] = make_float4(a0, a1, a2, a3);
        }
        __syncthreads();                                       // B2

        if (tid < H) {
            const int j = tid;
            float gi = s_gacc[0][j]         + s_gacc[1][j]         + s_gacc[2][j]         + s_gacc[3][j];
            float gf = s_gacc[0][H + j]     + s_gacc[1][H + j]     + s_gacc[2][H + j]     + s_gacc[3][H + j];
            float gg = s_gacc[0][2 * H + j] + s_gacc[1][2 * H + j] + s_gacc[2][2 * H + j] + s_gacc[3][2 * H + j];
            float go = s_gacc[0][3 * H + j] + s_gacc[1][3 * H + j] + s_gacc[2][3 * H + j] + s_gacc[3][3 * H + j];
            c0 = sigm(gf) * c0 + sigm(gi) * ftanh(gg);
            float h0 = sigm(go) * ftanh(c0);
            s_xh0[D + j] = h0;        // recurrent input for next step
            s_xh1[j]     = h0;        // layer-1 input now
        }
        __syncthreads();                                       // B3

        // ---- layer 1 partial gates ----
        {
            float a0 = bz1.x, a1 = bz1.y, a2 = bz1.z, a3 = bz1.w;
            const float* Wp = W1b;
            const float* xp = &s_xh1[kb * K1P];
            #pragma unroll 4
            for (int k0 = 0; k0 < K1P; k0 += 4) {
                float4 xv = *(const float4*)(xp + k0);
                float4 w0 = *(const float4*)(Wp);
                float4 w1 = *(const float4*)(Wp + G);
                float4 w2 = *(const float4*)(Wp + 2 * G);
                float4 w3 = *(const float4*)(Wp + 3 * G);
                Wp += 4 * G;
                a0 = fmaf(xv.x, w0.x, a0); a1 = fmaf(xv.x, w0.y, a1); a2 = fmaf(xv.x, w0.z, a2); a3 = fmaf(xv.x, w0.w, a3);
                a0 = fmaf(xv.y, w1.x, a0); a1 = fmaf(xv.y, w1.y, a1); a2 = fmaf(xv.y, w1.z, a2); a3 = fmaf(xv.y, w1.w, a3);
                a0 = fmaf(xv.z, w2.x, a0); a1 = fmaf(xv.z, w2.y, a1); a2 = fmaf(xv.z, w2.z, a2); a3 = fmaf(xv.z, w2.w, a3);
                a0 = fmaf(xv.w, w3.x, a0); a1 = fmaf(xv.w, w3.y, a1); a2 = fmaf(xv.w, w3.z, a2); a3 = fmaf(xv.w, w3.w, a3);
            }
            *(float4*)&s_gacc[kb][row0] = make_float4(a0, a1, a2, a3);
        }
        __syncthreads();                                       // B4

        if (tid < H) {
            const int j = tid;
            float gi = s_gacc[0][j]         + s_gacc[1][j]         + s_gacc[2][j]         + s_gacc[3][j];
            float gf = s_gacc[0][H + j]     + s_gacc[1][H + j]     + s_gacc[2][H + j]     + s_gacc[3][H + j];
            float gg = s_gacc[0][2 * H + j] + s_gacc[1][2 * H + j] + s_gacc[2][2 * H + j] + s_gacc[3][2 * H + j];
            float go = s_gacc[0][3 * H + j] + s_gacc[1][3 * H + j] + s_gacc[2][3 * H + j] + s_gacc[3][3 * H + j];
            c1 = sigm(gf) * c1 + sigm(gi) * ftanh(gg);
            float h1v = sigm(go) * ftanh(c1);
            s_xh1[H + j] = h1v;
            seq_out[((size_t)b * T + t) * H + j] = __float2bfloat16(h1v);
        }
        // next-iter B1 orders the h1/s_gacc hazards
    }
}

// ---------------- attention ----------------
// a2[b,k] = sum_h hT[b,h] * W2[h,k]
__global__ __launch_bounds__(256) void k_a2(const __hip_bfloat16* __restrict__ lstm_out,
                                            const float* __restrict__ W2,
                                            float* __restrict__ a2out)
{
    __shared__ float s_hT[H];
    int b = blockIdx.x;
    int k = threadIdx.x;
    const unsigned short* lp = (const unsigned short*)lstm_out;
    s_hT[k] = bf2f(lp[((size_t)b * T + (T - 1)) * H + k]);
    __syncthreads();
    float acc = 0.f;
    #pragma unroll 4
    for (int h = 0; h < H; ++h) acc += s_hT[h] * W2[h * H + k];
    a2out[b * H + k] = acc;
}

// scores[b,t] = sum_k tanh( (row_t @ W1)[k] + a2[b,k] ) * attn_w[k]
__global__ __launch_bounds__(256) void k_scores(const __hip_bfloat16* __restrict__ lstm_out,
                                                const float* __restrict__ W1,
                                                const float* __restrict__ a2,
                                                const float* __restrict__ attn_w,
                                                float* __restrict__ scores)
{
    const int RPB = 32;
    __shared__ float s_rows[RPB][H];   // 32 KB
    __shared__ float s_part[RPB][4];
    int b   = blockIdx.y;
    int t0  = blockIdx.x * RPB;
    int tid = threadIdx.x;

    const unsigned short* lp = (const unsigned short*)lstm_out + ((size_t)b * T + t0) * H;
    for (int i = tid; i < RPB * H / 4; i += 256) {
        ushort4 v = ((const ushort4*)lp)[i];
        int e  = i * 4;
        int r  = e >> 8;
        int h0 = e & 255;
        float4 f = make_float4(bf2f(v.x), bf2f(v.y), bf2f(v.z), bf2f(v.w));
        *(float4*)&s_rows[r][h0] = f;
    }
    __syncthreads();

    int c = tid;
    float acc[RPB];
    #pragma unroll
    for (int r = 0; r < RPB; ++r) acc[r] = 0.f;
    for (int h = 0; h < H; ++h) {
        float w = W1[h * H + c];
        #pragma unroll
        for (int r = 0; r < RPB; ++r) acc[r] += s_rows[r][h] * w;
    }
    float a2v = a2[b * H + c];
    float wc  = attn_w[c];
    int lane = tid & 63, wv = tid >> 6;
    #pragma unroll
    for (int r = 0; r < RPB; ++r) {
        float v = ftanh(acc[r] + a2v) * wc;
        for (int off = 32; off; off >>= 1) v += __shfl_down(v, off);
        if (lane == 0) s_part[r][wv] = v;
    }
    __syncthreads();
    if (tid < RPB) {
        float s = s_part[tid][0] + s_part[tid][1] + s_part[tid][2] + s_part[tid][3];
        scores[(size_t)b * T + t0 + tid] = s;
    }
}

// softmax over t, context, layernorm
__global__ __launch_bounds__(256) void k_finish(const __hip_bfloat16* __restrict__ lstm_out,
                                                const float* __restrict__ scores,
                                                const float* __restrict__ gamma,
                                                const float* __restrict__ beta,
                                                float* __restrict__ out)
{
    __shared__ float s_p[T];     // 8 KB
    __shared__ float s_red[4];
    const int b = blockIdx.x;
    const int tid = threadIdx.x;
    const int lane = tid & 63, wv = tid >> 6;

    const float* sc = scores + (size_t)b * T;
    float m = -1e30f;
    for (int t = tid; t < T; t += 256) m = fmaxf(m, sc[t]);
    for (int off = 32; off; off >>= 1) m = fmaxf(m, __shfl_down(m, off));
    if (lane == 0) s_red[wv] = m;
    __syncthreads();
    m = fmaxf(fmaxf(s_red[0], s_red[1]), fmaxf(s_red[2], s_red[3]));
    __syncthreads();

    float z = 0.f;
    for (int t = tid; t < T; t += 256) { float e = __expf(sc[t] - m); s_p[t] = e; z += e; }
    for (int off = 32; off; off >>= 1) z += __shfl_down(z, off);
    if (lane == 0) s_red[wv] = z;
    __syncthreads();
    z = s_red[0] + s_red[1] + s_red[2] + s_red[3];
    float rz = 1.0f / z;
    __syncthreads();

    const unsigned short* lp = (const unsigned short*)lstm_out + (size_t)b * T * H + tid;
    float ctx = 0.f;
    for (int t = 0; t < T; ++t) ctx += s_p[t] * bf2f(lp[(size_t)t * H]);
    ctx *= rz;

    float s1 = ctx;
    for (int off = 32; off; off >>= 1) s1 += __shfl_down(s1, off);
    if (lane == 0) s_red[wv] = s1;
    __syncthreads();
    float mu = (s_red[0] + s_red[1] + s_red[2] + s_red[3]) * (1.0f / H);
    __syncthreads();
    float dv = ctx - mu;
    float s2 = dv * dv;
    for (int off = 32; off; off >>= 1) s2 += __shfl_down(s2, off);
    if (lane == 0) s_red[wv] = s2;
    __syncthreads();
    float var = (s_red[0] + s_red[1] + s_red[2] + s_red[3]) * (1.0f / H);
    out[b * H + tid] = dv * rsqrtf(var + 1e-5f) * gamma[tid] + beta[tid];
}

// ---------------- host ----------------
extern "C" void kernel_launch(void* const* d_in, const int* in_sizes, int n_in,
                              void* d_out, int out_size, void* d_ws, size_t ws_size,
                              hipStream_t stream) {
    const float* x     = (const float*)d_in[0];
    const float* Wih0  = (const float*)d_in[1];
    const float* Whh0  = (const float*)d_in[2];
    const float* bih0  = (const float*)d_in[3];
    const float* bhh0  = (const float*)d_in[4];
    const float* Wih1  = (const float*)d_in[5];
    const float* Whh1  = (const float*)d_in[6];
    const float* bih1  = (const float*)d_in[7];
    const float* bhh1  = (const float*)d_in[8];
    const float* aW1   = (const float*)d_in[9];
    const float* aW2   = (const float*)d_in[10];
    const float* aw    = (const float*)d_in[11];
    const float* gamma = (const float*)d_in[12];
    const float* beta  = (const float*)d_in[13];
    float* out = (float*)d_out;

    // workspace layout (total ~68.3 MB)
    float* ws = (float*)d_ws;
    float* WT0     = ws;                          // 384*1024        = 393216 f
    float* WT1     = WT0 + (size_t)K0 * G;        // 512*1024        = 524288 f
    float* bsum0   = WT1 + (size_t)K1 * G;        // 1024
    float* bsum1   = bsum0 + G;                   // 1024
    float* a2buf   = bsum1 + G;                   // 64*256
    float* scoresb = a2buf + (size_t)B * H;       // 64*2048
    __hip_bfloat16* lstm2 = (__hip_bfloat16*)(scoresb + (size_t)B * T);  // B*T*H bf16 = 64 MB

    // prep: k-major combined weights + bias sums
    k_transpose<<<(D * G + 255) / 256, 256, 0, stream>>>(Wih0, WT0, D);
    k_transpose<<<(H * G + 255) / 256, 256, 0, stream>>>(Whh0, WT0 + (size_t)D * G, H);
    k_transpose<<<(H * G + 255) / 256, 256, 0, stream>>>(Wih1, WT1, H);
    k_transpose<<<(H * G + 255) / 256, 256, 0, stream>>>(Whh1, WT1 + (size_t)H * G, H);
    k_bias_sum<<<(G + 255) / 256, 256, 0, stream>>>(bih0, bhh0, bsum0, G);
    k_bias_sum<<<(G + 255) / 256, 256, 0, stream>>>(bih1, bhh1, bsum1, G);

    // fused 2-layer recurrence
    k_lstm_fused<<<B, 1024, 0, stream>>>(x, WT0, WT1, bsum0, bsum1, lstm2);

    // attention + layernorm
    k_a2<<<B, H, 0, stream>>>(lstm2, aW2, a2buf);
    k_scores<<<dim3(T / 32, B), 256, 0, stream>>>(lstm2, aW1, a2buf, aw, scoresb);
    k_finish<<<B, 256, 0, stream>>>(lstm2, scoresb, gamma, beta, out);
}